// Round 23
// baseline (48.858 us; speedup 1.0000x reference)
//
#include <hip/hip_runtime.h>

typedef _Float16 f16;
typedef __attribute__((ext_vector_type(2))) __fp16 fp16x2;
typedef __attribute__((ext_vector_type(8))) _Float16 f16x8;
typedef __attribute__((ext_vector_type(4))) float f32x4;
typedef __attribute__((ext_vector_type(4))) unsigned int u32x4;

#define NPTS   (16 * 32768)
#define PTSPB  96
#define NBLK   ((NPTS + PTSPB - 1) / PTSPB)   // 5462, last block 32 valid pts
// packed-weight layout in d_ws (bytes); weights stay in global (L2-resident, ~80KB)
#define W0P_OFF 0
#define W1P_OFF (16 * 1024)
#define W2P_OFF (48 * 1024)
#define WOP_OFF (80 * 1024)
#define FRAGS_BYTES (84 * 1024)
#define TENC_OFF FRAGS_BYTES          // in ws: 16 batches x 16 f32
#define WS_NEEDED (FRAGS_BYTES + 1024)
#define LDS_TOTAL 4096                // one wave per block -> single 4KB transpose scratch

// ---------------- pack kernel (r16-verified): weights -> f16 A-operand fragments ----------------
// A frag (mt,kt) at fi = interleaved index: lane l, elem j <-> W_sw[m = 16mt + (l&15)][k]
//   layer0 (natural k-map, matches 64-dim feature build): k = 32kt + 8*(l>>4) + j, kmax 55
//   layers 1,2,out (chained from D layout): k = 32kt + 16*(j>>2) + 4*(l>>4) + (j&3)
__global__ void pack_weights(const float* __restrict__ time, const float* __restrict__ te0,
                             const float* __restrict__ te1, const float* __restrict__ W0,
                             const float* __restrict__ W1, const float* __restrict__ W2,
                             const float* __restrict__ Wout, unsigned char* __restrict__ ws) {
  const int bi = blockIdx.x;
  const int l = threadIdx.x;
  const int g = l >> 4, r16 = l & 15;
  if (bi < 84) {
    const float* W; int obase, fi, kt, mt, kmax; bool natural, outcol;
    if (bi < 16)      { W = W0;   fi = bi;      mt = fi >> 1; kt = fi & 1; obase = W0P_OFF; kmax = 55;  natural = true;  outcol = false; }
    else if (bi < 48) { W = W1;   fi = bi - 16; mt = fi >> 2; kt = fi & 3; obase = W1P_OFF; kmax = 128; natural = false; outcol = false; }
    else if (bi < 80) { W = W2;   fi = bi - 48; mt = fi >> 2; kt = fi & 3; obase = W2P_OFF; kmax = 128; natural = false; outcol = false; }
    else              { W = Wout; fi = bi - 80; mt = 0;       kt = fi;     obase = WOP_OFF; kmax = 128; natural = false; outcol = true;  }
    const int m = mt * 16 + r16;
    // NOTE: frag storage index must match the consumer's flattened s = mt*KT + kt order.
    int KTl = (bi < 16) ? 2 : 4;
    int si = outcol ? kt : (mt * KTl + kt);
    f16 vals[8] __attribute__((aligned(16)));
#pragma unroll
    for (int j = 0; j < 8; ++j) {
      const int k = natural ? (kt * 32 + g * 8 + j)
                            : (kt * 32 + (j >> 2) * 16 + g * 4 + (j & 3));
      float v = 0.f;
      if (k < kmax) v = outcol ? ((m == 0) ? Wout[k] : 0.f) : W[k * 128 + m];
      vals[j] = (f16)v;
    }
    *(u32x4*)(ws + obase + (si * 64 + l) * 16) = *(const u32x4*)vals;
  } else {
    // time encoding table: 16 batches x 16 dims fp32
    const int idx = (bi - 84) * 64 + l;  // 0..255
    const int b = idx >> 4, d = idx & 15;
    const float t = time[b];
    const float* emb; int L, dd;
    if (d < 8) { emb = te0; L = 5;  dd = d; }
    else       { emb = te1; L = 20; dd = d - 8; }
    const float tL = t * (float)L;
    int i = (int)floorf(tL);
    i = i < 0 ? 0 : (i > L - 1 ? L - 1 : i);
    const float wlo = (float)(i + 1) - tL;
    float v = wlo * emb[i * 8 + dd] + (1.f - wlo) * emb[(i + 1) * 8 + dd];
    if (t >= 1.f) v = emb[L * 8 + dd];
    ((float*)(ws + TENC_OFF))[idx] = v;
  }
}

__device__ __forceinline__ unsigned int pkmax0(unsigned int x) {
  unsigned int r;
  asm("v_pk_max_f16 %0, %1, %2" : "=v"(r) : "v"(x), "v"(0u));
  return r;
}
__device__ __forceinline__ unsigned int pkrtz(float a, float b) {
  union { fp16x2 h; unsigned int u; } c;
  c.h = __builtin_amdgcn_cvt_pkrtz(a, b);
  return c.u;
}
__device__ __forceinline__ float hwsin_rev(float rev) {
  float r; asm("v_sin_f32 %0, %1" : "=v"(r) : "v"(rev)); return r;
}
__device__ __forceinline__ float hwcos_rev(float rev) {
  float r; asm("v_cos_f32 %0, %1" : "=v"(r) : "v"(rev)); return r;
}

// 64-dim feature row (r16 order: [tenc16, pts3, sin18, cos18, 0-pad]) -> 32 packed u32
__device__ __forceinline__ void build_feat(const float* __restrict__ xyz,
                                           const unsigned char* __restrict__ ws,
                                           int p, unsigned int* fw) {
  const float* tb = (const float*)(ws + TENC_OFF) + (p >> 15) * 16;  // batch = p/32768
  float ff[64];
#pragma unroll
  for (int i = 0; i < 16; ++i) ff[i] = tb[i];
  const float xs0 = xyz[p * 3], xs1 = xyz[p * 3 + 1], xs2 = xyz[p * 3 + 2];
  const float pcs[3] = {(xs0 + 1.f) * 0.5f, (xs1 + 1.f) * 0.5f, (xs2 + 1.f) * 0.5f};
  const float INV2PI = 0.15915494309189535f;
#pragma unroll
  for (int c = 0; c < 3; ++c) {
    ff[16 + c] = pcs[c];
    float s = hwsin_rev(pcs[c] * INV2PI), co = hwcos_rev(pcs[c] * INV2PI);
#pragma unroll
    for (int f = 0; f < 6; ++f) {
      ff[19 + f * 3 + c] = s;
      ff[37 + f * 3 + c] = co;
      const float s2 = 2.f * s * co, c2 = 1.f - 2.f * s * s;
      s = s2; co = c2;
    }
  }
#pragma unroll
  for (int i = 55; i < 64; ++i) ff[i] = 0.f;
#pragma unroll
  for (int i = 0; i < 32; ++i) fw[i] = pkrtz(ff[2 * i], ff[2 * i + 1]);
}

// ---------------- one swapped hidden layer, 6 N-tiles (96 points): D = W_sw(128xK) * B(Kx96) ----------------
// Single-strip accumulation (8 serial 16-row m-strips); each A-frag load feeds 6 MFMAs
// (1.5x the 64-pt ratio); 2-slot depth-1 prefetch (register-lean; depth measured ~null);
// bias as C-init; epilogue fills half of Bout[mt>>1][nt] per strip (union RMW).
template <int KT>
__device__ __forceinline__ void layer_swapped(const unsigned char* __restrict__ wsrc,
                                              const float* __restrict__ bias,
                                              const f16x8 (&Bin)[KT][6], f16x8 (&Bout)[4][6],
                                              int lane) {
  const int g4 = (lane >> 4) * 4;
  f16x8 Ab[2];
  Ab[0] = *(const f16x8*)(wsrc + (0 * 64 + lane) * 16);
#pragma unroll
  for (int mt = 0; mt < 8; ++mt) {
    const float4 bv = *(const float4*)(bias + mt * 16 + g4);
    f32x4 acc[6];
#pragma unroll
    for (int nt = 0; nt < 6; ++nt) acc[nt] = (f32x4){bv.x, bv.y, bv.z, bv.w};
#pragma unroll
    for (int kt = 0; kt < KT; ++kt) {
      const int s = mt * KT + kt;
      if (s + 1 < 8 * KT)
        Ab[(s + 1) & 1] = *(const f16x8*)(wsrc + ((s + 1) * 64 + lane) * 16);
      __builtin_amdgcn_s_setprio(1);
#pragma unroll
      for (int nt = 0; nt < 6; ++nt)
        acc[nt] = __builtin_amdgcn_mfma_f32_16x16x32_f16(Ab[s & 1], Bin[kt][nt], acc[nt], 0, 0, 0);
      __builtin_amdgcn_s_setprio(0);
    }
#pragma unroll
    for (int nt = 0; nt < 6; ++nt) {
      union { f16x8 v; unsigned int w[4]; } ub;
      ub.v = Bout[mt >> 1][nt];
      ub.w[2 * (mt & 1) + 0] = pkmax0(pkrtz(acc[nt][0], acc[nt][1]));
      ub.w[2 * (mt & 1) + 1] = pkmax0(pkrtz(acc[nt][2], acc[nt][3]));
      Bout[mt >> 1][nt] = ub.v;
    }
  }
}

// ---------------- fused main kernel: 1-wave blocks, 96 points/wave, weights from L2 ----------------
// __launch_bounds__(64, 2): total-reg cap 512/2 = 256/wave (unified-file law, r15/r21).
// Peak live ~ Bin96 + Bout96 + acc24 + misc ~ 235 <= 256 -> 2 waves/SIMD retained while
// weight bytes/point drop x2/3 and MFMA:load ratio rises 1.5x.
// Tripwire: FETCH >> 4MB = spill cliff -> this direction is dead.
__global__ void __launch_bounds__(64, 2)
mlp_main(const float* __restrict__ xyz, const float* __restrict__ b0,
         const float* __restrict__ b1, const float* __restrict__ b2,
         const float* __restrict__ bout, const unsigned char* __restrict__ ws,
         float* __restrict__ out) {
  extern __shared__ char lds[];
  const int lane = threadIdx.x;
  const int g = lane >> 4, r16 = lane & 15;
  char* scr = lds;  // 32 rows x 128B transpose scratch
  const float bo = bout[0];

  const int pbase = blockIdx.x * PTSPB;

  // ---- pass A: points 0..63 (one per lane) ----
  unsigned int fw[32];
  {
    int p = pbase + lane; p = p < NPTS ? p : NPTS - 1;
    build_feat(xyz, ws, p, fw);
  }
  f16x8 B0[2][6];
#pragma unroll
  for (int h = 0; h < 2; ++h) {
    if ((lane >> 5) == h) {
#pragma unroll
      for (int s = 0; s < 8; ++s)
        *(u32x4*)(scr + (lane & 31) * 128 + ((s ^ (lane & 7)) * 16)) = ((const u32x4*)fw)[s];
    }
    asm volatile("s_waitcnt lgkmcnt(0)" ::: "memory");
#pragma unroll
    for (int kt = 0; kt < 2; ++kt)
#pragma unroll
      for (int nn = 0; nn < 2; ++nn) {
        const int row = nn * 16 + r16;
        B0[kt][h * 2 + nn] = *(const f16x8*)(scr + row * 128 + (((4 * kt + g) ^ (row & 7)) * 16));
      }
    asm volatile("s_waitcnt lgkmcnt(0)" ::: "memory");
  }
  // ---- pass B: points 64..95 (lanes 0..31 own one point; 32..63 duplicate) ----
  {
    int p = pbase + 64 + (lane & 31); p = p < NPTS ? p : NPTS - 1;
    build_feat(xyz, ws, p, fw);
  }
  if (lane < 32) {
#pragma unroll
    for (int s = 0; s < 8; ++s)
      *(u32x4*)(scr + (lane & 31) * 128 + ((s ^ (lane & 7)) * 16)) = ((const u32x4*)fw)[s];
  }
  asm volatile("s_waitcnt lgkmcnt(0)" ::: "memory");
#pragma unroll
  for (int kt = 0; kt < 2; ++kt)
#pragma unroll
    for (int nn = 0; nn < 2; ++nn) {
      const int row = nn * 16 + r16;
      B0[kt][4 + nn] = *(const f16x8*)(scr + row * 128 + (((4 * kt + g) ^ (row & 7)) * 16));
    }
  asm volatile("s_waitcnt lgkmcnt(0)" ::: "memory");

  // ---- 3 hidden layers, register-chained, weights streamed from L2 ----
  f16x8 Bx[4][6], By[4][6];
  layer_swapped<2>(ws + W0P_OFF, b0, B0, Bx, lane);
  layer_swapped<4>(ws + W1P_OFF, b1, Bx, By, lane);
  layer_swapped<4>(ws + W2P_OFF, b2, By, Bx, lane);

  // ---- output layer (M=16 padded, row 0 real): 2-slot prefetch, bias as C ----
  f16x8 Ob[2];
  Ob[0] = *(const f16x8*)(ws + WOP_OFF + (0 * 64 + lane) * 16);
  const f32x4 bovec = (f32x4){bo, bo, bo, bo};
  f32x4 accO[6];
#pragma unroll
  for (int kt = 0; kt < 4; ++kt) {
    if (kt + 1 < 4)
      Ob[(kt + 1) & 1] = *(const f16x8*)(ws + WOP_OFF + ((kt + 1) * 64 + lane) * 16);
    __builtin_amdgcn_s_setprio(1);
    if (kt == 0) {
#pragma unroll
      for (int nt = 0; nt < 6; ++nt)
        accO[nt] = __builtin_amdgcn_mfma_f32_16x16x32_f16(Ob[0], Bx[0][nt], bovec, 0, 0, 0);
    } else {
#pragma unroll
      for (int nt = 0; nt < 6; ++nt)
        accO[nt] = __builtin_amdgcn_mfma_f32_16x16x32_f16(Ob[kt & 1], Bx[kt][nt], accO[nt], 0, 0, 0);
    }
    __builtin_amdgcn_s_setprio(0);
  }

  // ---- stores: tiles 0..3 full-wave, tiles 4..5 half-wave; tail-guarded ----
  {
    const float a0 = __shfl(accO[0][0], r16, 64);
    const float a1 = __shfl(accO[1][0], r16, 64);
    const float a2 = __shfl(accO[2][0], r16, 64);
    const float a3 = __shfl(accO[3][0], r16, 64);
    const float v = g == 0 ? a0 : g == 1 ? a1 : g == 2 ? a2 : a3;
    if (pbase + lane < NPTS) out[pbase + lane] = v;
  }
  {
    const float a4 = __shfl(accO[4][0], r16, 64);
    const float a5 = __shfl(accO[5][0], r16, 64);
    const float v = ((lane >> 4) & 1) ? a5 : a4;
    const int p = pbase + 64 + lane;
    if (lane < 32 && p < NPTS) out[p] = v;
  }
}

extern "C" void kernel_launch(void* const* d_in, const int* in_sizes, int n_in,
                              void* d_out, int out_size, void* d_ws, size_t ws_size,
                              hipStream_t stream) {
  const float* time = (const float*)d_in[0];
  const float* xyz  = (const float*)d_in[1];
  const float* te0  = (const float*)d_in[2];
  const float* te1  = (const float*)d_in[3];
  const float* W0   = (const float*)d_in[4];
  const float* b0   = (const float*)d_in[5];
  const float* W1   = (const float*)d_in[6];
  const float* b1   = (const float*)d_in[7];
  const float* W2   = (const float*)d_in[8];
  const float* b2   = (const float*)d_in[9];
  const float* Wout = (const float*)d_in[10];
  const float* bout = (const float*)d_in[11];
  float* out = (float*)d_out;
  unsigned char* ws = (unsigned char*)d_ws;
  if (ws_size < WS_NEEDED) return;

  pack_weights<<<88, 64, 0, stream>>>(time, te0, te1, W0, W1, W2, Wout, ws);
  mlp_main<<<NBLK, 64, LDS_TOTAL, stream>>>(xyz, b0, b1, b2, bout, ws, out);
}

// Round 24
// 44.824 us; speedup vs baseline: 1.0900x; 1.0900x over previous
//
#include <hip/hip_runtime.h>

typedef _Float16 f16;
typedef __attribute__((ext_vector_type(2))) __fp16 fp16x2;
typedef __attribute__((ext_vector_type(8))) _Float16 f16x8;
typedef __attribute__((ext_vector_type(4))) float f32x4;
typedef __attribute__((ext_vector_type(4))) unsigned int u32x4;

#define NPTS   (16 * 32768)
// packed-weight layout in d_ws (bytes); weights stay in global (L2-resident, ~80KB)
#define W0P_OFF 0
#define W1P_OFF (16 * 1024)
#define W2P_OFF (48 * 1024)
#define WOP_OFF (80 * 1024)
#define FRAGS_BYTES (84 * 1024)
#define B0E_OFF FRAGS_BYTES           // in ws: 16 batches x 128 f32 effective layer-0 bias
#define WS_NEEDED (FRAGS_BYTES + 8192)
// LDS: 4 waves x 4KB transpose scratch
#define LDS_TOTAL (4 * 4096)

// ---------------- pack kernel: weights -> f16 A-operand fragments (W^T) ----------------
// A frag (mt,kt) stored at index fi = mt*KT + kt: lane l, elem j <-> W_sw[m = 16mt + (l&15)][k]
//   layer0 (natural k-map): k = 32kt + 8*(l>>4) + j ; covers the 39 xyz dims
//     (orig W0 row = 16 + k; tenc rows folded into b0_eff, blocks 84..115)
//   layers 1,2,out (chained from D layout): k = 32kt + 16*(j>>2) + 4*(l>>4) + (j&3)
__global__ void pack_weights(const float* __restrict__ time, const float* __restrict__ te0,
                             const float* __restrict__ te1, const float* __restrict__ W0,
                             const float* __restrict__ b0, const float* __restrict__ W1,
                             const float* __restrict__ W2, const float* __restrict__ Wout,
                             unsigned char* __restrict__ ws) {
  const int bi = blockIdx.x;
  const int l = threadIdx.x;
  const int g = l >> 4, r16 = l & 15;
  if (bi < 84) {
    const float* W; int obase, fi, kt, mt, kmax; bool natural, outcol;
    if (bi < 16)      { W = W0;   fi = bi;      mt = fi >> 1; kt = fi & 1; obase = W0P_OFF; kmax = 39;  natural = true;  outcol = false; }
    else if (bi < 48) { W = W1;   fi = bi - 16; mt = fi >> 2; kt = fi & 3; obase = W1P_OFF; kmax = 128; natural = false; outcol = false; }
    else if (bi < 80) { W = W2;   fi = bi - 48; mt = fi >> 2; kt = fi & 3; obase = W2P_OFF; kmax = 128; natural = false; outcol = false; }
    else              { W = Wout; fi = bi - 80; mt = 0;       kt = fi;     obase = WOP_OFF; kmax = 128; natural = false; outcol = true;  }
    const int m = mt * 16 + r16;
    f16 vals[8] __attribute__((aligned(16)));
#pragma unroll
    for (int j = 0; j < 8; ++j) {
      const int k = natural ? (kt * 32 + g * 8 + j)
                            : (kt * 32 + (j >> 2) * 16 + g * 4 + (j & 3));
      float v = 0.f;
      if (k < kmax) {
        if (outcol)       v = (m == 0) ? Wout[k] : 0.f;
        else if (natural) v = W[(16 + k) * 128 + m];   // layer0: skip tenc rows
        else              v = W[k * 128 + m];
      }
      vals[j] = (f16)v;
    }
    *(u32x4*)(ws + obase + (fi * 64 + l) * 16) = *(const u32x4*)vals;
  } else {
    // b0_eff[b][m] = b0[m] + sum_d tenc[b][d] * W0[d][m],  d = 0..15 (orig rows)
    const int idx = (bi - 84) * 64 + l;  // 0..2047
    const int b = idx >> 7, m = idx & 127;
    const float t = time[b];
    float acc = b0[m];
#pragma unroll
    for (int d = 0; d < 16; ++d) {
      const float* emb; int L, dd;
      if (d < 8) { emb = te0; L = 5;  dd = d; }
      else       { emb = te1; L = 20; dd = d - 8; }
      const float tL = t * (float)L;
      int i = (int)floorf(tL);
      i = i < 0 ? 0 : (i > L - 1 ? L - 1 : i);
      const float wlo = (float)(i + 1) - tL;
      float v = wlo * emb[i * 8 + dd] + (1.f - wlo) * emb[(i + 1) * 8 + dd];
      if (t >= 1.f) v = emb[L * 8 + dd];
      acc += v * W0[d * 128 + m];
    }
    ((float*)(ws + B0E_OFF))[b * 128 + m] = acc;
  }
}

// packed relu: max of two f16 halves vs 0 (exact: relu commutes with RTZ rounding)
__device__ __forceinline__ unsigned int pkmax0(unsigned int x) {
  unsigned int r;
  asm("v_pk_max_f16 %0, %1, %2" : "=v"(r) : "v"(x), "v"(0u));
  return r;
}
__device__ __forceinline__ unsigned int pkrtz(float a, float b) {
  union { fp16x2 h; unsigned int u; } c;
  c.h = __builtin_amdgcn_cvt_pkrtz(a, b);
  return c.u;
}
// HW transcendentals: v_sin/v_cos take revolutions (input * 2pi). x in [0,1] here.
__device__ __forceinline__ float hwsin_rev(float rev) {
  float r; asm("v_sin_f32 %0, %1" : "=v"(r) : "v"(rev)); return r;
}
__device__ __forceinline__ float hwcos_rev(float rev) {
  float r; asm("v_cos_f32 %0, %1" : "=v"(r) : "v"(rev)); return r;
}

// ---------------- one swapped hidden layer (r22 structure): D = W_sw(128xK) * Bin(Kx64) ----------------
// Single-strip accumulation (8 serial 16-row m-strips, acc[4]); 5-slot depth-4 A-frag
// prefetch; one float4 bias per strip as C-init; epilogue fills half of Bout[mt>>1][nt]
// per strip (union RMW, compile-time lanes).
template <int KT>
__device__ __forceinline__ void layer_swapped(const unsigned char* __restrict__ wsrc,
                                              const float* __restrict__ bias,
                                              const f16x8 (&Bin)[KT][4], f16x8 (&Bout)[4][4],
                                              int lane) {
  const int g4 = (lane >> 4) * 4;
  f16x8 Ab[5];
#pragma unroll
  for (int s = 0; s < 4; ++s)
    Ab[s] = *(const f16x8*)(wsrc + (s * 64 + lane) * 16);
#pragma unroll
  for (int mt = 0; mt < 8; ++mt) {
    const float4 bv = *(const float4*)(bias + mt * 16 + g4);
    f32x4 acc[4];
#pragma unroll
    for (int nt = 0; nt < 4; ++nt) acc[nt] = (f32x4){bv.x, bv.y, bv.z, bv.w};
#pragma unroll
    for (int kt = 0; kt < KT; ++kt) {
      const int s = mt * KT + kt;
      if (s + 4 < 8 * KT)
        Ab[(s + 4) % 5] = *(const f16x8*)(wsrc + ((s + 4) * 64 + lane) * 16);
      __builtin_amdgcn_s_setprio(1);
#pragma unroll
      for (int nt = 0; nt < 4; ++nt)
        acc[nt] = __builtin_amdgcn_mfma_f32_16x16x32_f16(Ab[s % 5], Bin[kt][nt], acc[nt], 0, 0, 0);
      __builtin_amdgcn_s_setprio(0);
    }
#pragma unroll
    for (int nt = 0; nt < 4; ++nt) {
      union { f16x8 v; unsigned int w[4]; } ub;
      ub.v = Bout[mt >> 1][nt];
      ub.w[2 * (mt & 1) + 0] = pkmax0(pkrtz(acc[nt][0], acc[nt][1]));
      ub.w[2 * (mt & 1) + 1] = pkmax0(pkrtz(acc[nt][2], acc[nt][3]));
      Bout[mt >> 1][nt] = ub.v;
    }
  }
}

// ---------------- fused main kernel: 4-wave PHASE-ALIGNED blocks, weights from L2 ----------------
// Each wave = one 64-pt task (identical r22 per-wave code). __syncthreads() at layer
// boundaries keeps the 4 waves' weight streams within a few steps of each other ->
// one wave's L1 miss becomes the others' L1 hit (L1 32KB < 84KB stream; uncorrelated
// phases thrash it — the hypothesized residual stall).
// __launch_bounds__(256,3): total-reg cap = 2048/(4 waves x 3) ~= 170/wave — the same
// cap that produced r21/r22's lean codegen (no lazy AGPR padding).
// Tripwire: FETCH >> 3.5MB = spill cliff -> revert to r22.
__global__ void __launch_bounds__(256, 3)
mlp_main(const float* __restrict__ xyz, const float* __restrict__ b1,
         const float* __restrict__ b2, const float* __restrict__ bout,
         const unsigned char* __restrict__ ws, float* __restrict__ out) {
  extern __shared__ char lds[];
  const int tid = threadIdx.x;
  const int lane = tid & 63, wv = tid >> 6;
  const int g = lane >> 4, r16 = lane & 15;

  char* scr = lds + wv * 4096;  // per-wave private transpose scratch (32 rows x 128B)
  const float bo = bout[0];

  const int pbase = blockIdx.x * 256 + wv * 64;
  const int p = pbase + lane;

  // ---- 39-dim xyz feature row in f32 (tenc folded into b0_eff), pack with cvt_pkrtz ----
  float ff[40];
  const float xs0 = xyz[p * 3], xs1 = xyz[p * 3 + 1], xs2 = xyz[p * 3 + 2];
  const float pcs[3] = {(xs0 + 1.f) * 0.5f, (xs1 + 1.f) * 0.5f, (xs2 + 1.f) * 0.5f};
  const float INV2PI = 0.15915494309189535f;
#pragma unroll
  for (int c = 0; c < 3; ++c) {
    ff[c] = pcs[c];
    const float rev = pcs[c] * INV2PI;
    float s = hwsin_rev(rev), co = hwcos_rev(rev);
#pragma unroll
    for (int f = 0; f < 6; ++f) {
      ff[3 + f * 3 + c] = s;
      ff[21 + f * 3 + c] = co;
      const float s2 = 2.f * s * co, c2 = 1.f - 2.f * s * s;
      s = s2; co = c2;
    }
  }
  ff[39] = 0.f;
  unsigned int fw[32];
#pragma unroll
  for (int i = 0; i < 20; ++i) fw[i] = pkrtz(ff[2 * i], ff[2 * i + 1]);
#pragma unroll
  for (int i = 20; i < 32; ++i) fw[i] = 0u;

  // ---- transpose via per-wave scratch, two 32-point halves (wave-internal sync) ----
  f16x8 B0[2][4];
#pragma unroll
  for (int h = 0; h < 2; ++h) {
    if ((lane >> 5) == h) {
#pragma unroll
      for (int s = 0; s < 8; ++s)
        *(u32x4*)(scr + (lane & 31) * 128 + ((s ^ (lane & 7)) * 16)) = ((const u32x4*)fw)[s];
    }
    asm volatile("s_waitcnt lgkmcnt(0)" ::: "memory");
#pragma unroll
    for (int kt = 0; kt < 2; ++kt)
#pragma unroll
      for (int nn = 0; nn < 2; ++nn) {
        const int row = nn * 16 + r16;
        B0[kt][h * 2 + nn] = *(const f16x8*)(scr + row * 128 + (((4 * kt + g) ^ (row & 7)) * 16));
      }
    asm volatile("s_waitcnt lgkmcnt(0)" ::: "memory");
  }

  // ---- 3 hidden layers; per-layer barriers phase-align the 4 waves' weight streams ----
  const float* b0e = (const float*)(ws + B0E_OFF) + (blockIdx.x >> 7) * 128;  // batch = pbase/32768
  f16x8 Bx[4][4], By[4][4];
  __syncthreads();
  layer_swapped<2>(ws + W0P_OFF, b0e, B0, Bx, lane);
  __syncthreads();
  layer_swapped<4>(ws + W1P_OFF, b1, Bx, By, lane);
  __syncthreads();
  layer_swapped<4>(ws + W2P_OFF, b2, By, Bx, lane);

  // ---- output layer (M=16 padded, only row 0 real): preload all 4 frags, bias as C ----
  f16x8 Ob[4];
#pragma unroll
  for (int kt = 0; kt < 4; ++kt)
    Ob[kt] = *(const f16x8*)(ws + WOP_OFF + (kt * 64 + lane) * 16);
  const f32x4 bovec = (f32x4){bo, bo, bo, bo};
  f32x4 accO[4];
  __builtin_amdgcn_s_setprio(1);
#pragma unroll
  for (int nt = 0; nt < 4; ++nt)
    accO[nt] = __builtin_amdgcn_mfma_f32_16x16x32_f16(Ob[0], Bx[0][nt], bovec, 0, 0, 0);
#pragma unroll
  for (int kt = 1; kt < 4; ++kt) {
#pragma unroll
    for (int nt = 0; nt < 4; ++nt)
      accO[nt] = __builtin_amdgcn_mfma_f32_16x16x32_f16(Ob[kt], Bx[kt][nt], accO[nt], 0, 0, 0);
  }
  __builtin_amdgcn_s_setprio(0);

  // ---- coalesced store: broadcast row-0 values, one 256B wave store ----
  const float a0 = __shfl(accO[0][0], r16, 64);
  const float a1 = __shfl(accO[1][0], r16, 64);
  const float a2 = __shfl(accO[2][0], r16, 64);
  const float a3 = __shfl(accO[3][0], r16, 64);
  const float v = g == 0 ? a0 : g == 1 ? a1 : g == 2 ? a2 : a3;
  out[pbase + lane] = v;
}

extern "C" void kernel_launch(void* const* d_in, const int* in_sizes, int n_in,
                              void* d_out, int out_size, void* d_ws, size_t ws_size,
                              hipStream_t stream) {
  const float* time = (const float*)d_in[0];
  const float* xyz  = (const float*)d_in[1];
  const float* te0  = (const float*)d_in[2];
  const float* te1  = (const float*)d_in[3];
  const float* W0   = (const float*)d_in[4];
  const float* b0   = (const float*)d_in[5];
  const float* W1   = (const float*)d_in[6];
  const float* b1   = (const float*)d_in[7];
  const float* W2   = (const float*)d_in[8];
  const float* b2   = (const float*)d_in[9];
  const float* Wout = (const float*)d_in[10];
  const float* bout = (const float*)d_in[11];
  float* out = (float*)d_out;
  unsigned char* ws = (unsigned char*)d_ws;
  if (ws_size < WS_NEEDED) return;

  // 84 weight-frag blocks + 32 blocks computing b0_eff (16 batches x 128)
  pack_weights<<<116, 64, 0, stream>>>(time, te0, te1, W0, b0, W1, W2, Wout, ws);
  mlp_main<<<NPTS / 256, 256, LDS_TOTAL, stream>>>(xyz, b1, b2, bout, ws, out);
}